// Round 1
// baseline (4971.262 us; speedup 1.0000x reference)
//
#include <hip/hip_runtime.h>
#include <hip/hip_bf16.h>

// SEAL GCN: 3x GraphConv(norm=both) -> SumPool(graph_id, sorted) -> MLP(128->128 relu ->200)
// N=50000 nodes, E=800000 edges, feat=128, 512 graphs. All fp32.

#define FEAT 128
#define NG 512

// ---------------- degree + norm ----------------
__global__ void k_degree(const int* __restrict__ src, const int* __restrict__ dst,
                         float* __restrict__ deg_out, float* __restrict__ deg_in, int E) {
    int e = blockIdx.x * blockDim.x + threadIdx.x;
    if (e < E) {
        atomicAdd(&deg_out[src[e]], 1.0f);
        atomicAdd(&deg_in[dst[e]], 1.0f);
    }
}

__global__ void k_norm(float* __restrict__ a, float* __restrict__ b, int N) {
    int i = blockIdx.x * blockDim.x + threadIdx.x;
    if (i < N) {
        a[i] = rsqrtf(fmaxf(a[i], 1.0f));
        b[i] = rsqrtf(fmaxf(b[i], 1.0f));
    }
}

// ---------------- build x = concat(init_embed[nid], z_table[z]) ----------------
// one thread per float4: i = node, q in [0,32) covers 128 floats
__global__ void k_build_x(const int* __restrict__ nid, const int* __restrict__ z,
                          const float* __restrict__ emb, const float* __restrict__ zt,
                          float* __restrict__ x, int N) {
    int tid = blockIdx.x * blockDim.x + threadIdx.x;
    int i = tid >> 5, q = tid & 31;
    if (i < N) {
        float4 v;
        if (q < 16) v = ((const float4*)emb)[(size_t)nid[i] * 16 + q];
        else        v = ((const float4*)zt)[(size_t)z[i] * 16 + (q - 16)];
        ((float4*)x)[(size_t)i * 32 + q] = v;
    }
}

// ---------------- SpMM scatter: agg[dst] += x[src] * norm_out[src] ----------------
__global__ void k_scatter(const float* __restrict__ x, const float* __restrict__ nout,
                          const int* __restrict__ src, const int* __restrict__ dst,
                          float* __restrict__ agg, int E) {
    int tid = blockIdx.x * blockDim.x + threadIdx.x;
    int e = tid >> 5, q = tid & 31;
    if (e < E) {
        int s = src[e], d = dst[e];
        float w = nout[s];
        float4 v = ((const float4*)x)[(size_t)s * 32 + q];
        float* p = agg + (size_t)d * FEAT + q * 4;
        atomicAdd(p + 0, v.x * w);
        atomicAdd(p + 1, v.y * w);
        atomicAdd(p + 2, v.z * w);
        atomicAdd(p + 3, v.w * w);
    }
}

// ---------------- per-node GEMM: y[i,:] = relu?((agg[i,:]*nin[i]) @ W + b) ----------------
// 32 nodes per block, 256 threads: thread = (node r = tid>>3, col group g = tid&7),
// covers cols [g*16, g*16+16) as 4 float4 accumulators.
__global__ __launch_bounds__(256) void k_gemm_node(
        const float* __restrict__ a, const float* __restrict__ nin,
        const float* __restrict__ W, const float* __restrict__ b,
        float* __restrict__ y, int N, int relu) {
    __shared__ float as[32][129];   // +1 pad: node stride 128 would alias all rows to one bank
    int nb = blockIdx.x * 32;
    int tid = threadIdx.x;

    // stage 32 scaled rows: 32 rows x 32 float4
    for (int t = tid; t < 32 * 32; t += 256) {
        int r = t >> 5, q = t & 31;
        int node = nb + r;
        float4 v = make_float4(0.f, 0.f, 0.f, 0.f);
        float s = 0.f;
        if (node < N) {
            v = ((const float4*)a)[(size_t)node * 32 + q];
            s = nin[node];
        }
        as[r][q * 4 + 0] = v.x * s;
        as[r][q * 4 + 1] = v.y * s;
        as[r][q * 4 + 2] = v.z * s;
        as[r][q * 4 + 3] = v.w * s;
    }
    __syncthreads();

    int r = tid >> 3;
    int g = tid & 7;
    int node = nb + r;

    float4 acc[4];
    #pragma unroll
    for (int c = 0; c < 4; c++) acc[c] = ((const float4*)b)[g * 4 + c];

    for (int k = 0; k < FEAT; k++) {
        float av = as[r][k];
        const float4* wr = (const float4*)(W + (size_t)k * FEAT) + g * 4;
        #pragma unroll
        for (int c = 0; c < 4; c++) {
            float4 wv = wr[c];
            acc[c].x += av * wv.x;
            acc[c].y += av * wv.y;
            acc[c].z += av * wv.z;
            acc[c].w += av * wv.w;
        }
    }

    if (node < N) {
        float4* yp = (float4*)(y + (size_t)node * FEAT) + g * 4;
        #pragma unroll
        for (int c = 0; c < 4; c++) {
            float4 v = acc[c];
            if (relu) {
                v.x = fmaxf(v.x, 0.f); v.y = fmaxf(v.y, 0.f);
                v.z = fmaxf(v.z, 0.f); v.w = fmaxf(v.w, 0.f);
            }
            yp[c] = v;
        }
    }
}

// ---------------- sum-pool over graph_id ----------------
__global__ void k_pool(const float* __restrict__ x, const int* __restrict__ gid,
                       float* __restrict__ g, int N) {
    int tid = blockIdx.x * blockDim.x + threadIdx.x;
    int i = tid >> 5, q = tid & 31;
    if (i < N) {
        int gg = gid[i];
        float4 v = ((const float4*)x)[(size_t)i * 32 + q];
        float* p = g + (size_t)gg * FEAT + q * 4;
        atomicAdd(p + 0, v.x);
        atomicAdd(p + 1, v.y);
        atomicAdd(p + 2, v.z);
        atomicAdd(p + 3, v.w);
    }
}

// ---------------- MLP head ----------------
__global__ void k_lin1(const float* __restrict__ g, const float* __restrict__ W,
                       const float* __restrict__ b, float* __restrict__ h) {
    __shared__ float gs[128];
    int gi = blockIdx.x, j = threadIdx.x;
    gs[j] = g[(size_t)gi * 128 + j];
    __syncthreads();
    float acc = b[j];
    for (int k = 0; k < 128; k++) acc += gs[k] * W[(size_t)k * 128 + j];
    h[(size_t)gi * 128 + j] = fmaxf(acc, 0.f);
}

__global__ void k_lin2(const float* __restrict__ h, const float* __restrict__ W,
                       const float* __restrict__ b, float* __restrict__ out) {
    __shared__ float hs[128];
    int gi = blockIdx.x, j = threadIdx.x;
    if (j < 128) hs[j] = h[(size_t)gi * 128 + j];
    __syncthreads();
    if (j < 200) {
        float acc = b[j];
        for (int k = 0; k < 128; k++) acc += hs[k] * W[(size_t)k * 200 + j];
        out[(size_t)gi * 200 + j] = acc;
    }
}

extern "C" void kernel_launch(void* const* d_in, const int* in_sizes, int n_in,
                              void* d_out, int out_size, void* d_ws, size_t ws_size,
                              hipStream_t stream) {
    const int*   nid = (const int*)d_in[0];
    const int*   z   = (const int*)d_in[1];
    const int*   src = (const int*)d_in[2];
    const int*   dst = (const int*)d_in[3];
    const int*   gid = (const int*)d_in[4];
    const float* emb = (const float*)d_in[5];
    const float* zt  = (const float*)d_in[6];
    const float* W0  = (const float*)d_in[7];
    const float* b0  = (const float*)d_in[8];
    const float* W1  = (const float*)d_in[9];
    const float* b1  = (const float*)d_in[10];
    const float* W2  = (const float*)d_in[11];
    const float* b2  = (const float*)d_in[12];
    const float* l1W = (const float*)d_in[13];
    const float* l1b = (const float*)d_in[14];
    const float* l2W = (const float*)d_in[15];
    const float* l2b = (const float*)d_in[16];
    float* out = (float*)d_out;

    const int N = in_sizes[0];
    const int E = in_sizes[2];

    // workspace layout (fp32, 64-elt aligned)
    size_t NA = (size_t)((N + 63) & ~63);
    float* norm_out = (float*)d_ws;         // [NA]
    float* norm_in  = norm_out + NA;        // [NA]
    float* xA  = norm_in + NA;              // [N*128]
    float* xB  = xA + (size_t)N * FEAT;     // [N*128]
    float* agg = xB + (size_t)N * FEAT;     // [N*128]
    float* gb  = agg + (size_t)N * FEAT;    // [512*128]
    float* h1  = gb + (size_t)NG * FEAT;    // [512*128]

    // degrees -> norms (shared by all 3 layers)
    hipMemsetAsync(norm_out, 0, 2 * NA * sizeof(float), stream);
    k_degree<<<(E + 255) / 256, 256, 0, stream>>>(src, dst, norm_out, norm_in, E);
    k_norm<<<(N + 255) / 256, 256, 0, stream>>>(norm_out, norm_in, N);

    // x0
    int nthr = N * 32;
    k_build_x<<<(nthr + 255) / 256, 256, 0, stream>>>(nid, z, emb, zt, xA, N);

    int sthr_blocks = (int)(((size_t)E * 32 + 255) / 256);
    int gemm_blocks = (N + 31) / 32;

    // layer 0: xA -> xB (relu)
    hipMemsetAsync(agg, 0, (size_t)N * FEAT * sizeof(float), stream);
    k_scatter<<<sthr_blocks, 256, 0, stream>>>(xA, norm_out, src, dst, agg, E);
    k_gemm_node<<<gemm_blocks, 256, 0, stream>>>(agg, norm_in, W0, b0, xB, N, 1);

    // layer 1: xB -> xA (relu)
    hipMemsetAsync(agg, 0, (size_t)N * FEAT * sizeof(float), stream);
    k_scatter<<<sthr_blocks, 256, 0, stream>>>(xB, norm_out, src, dst, agg, E);
    k_gemm_node<<<gemm_blocks, 256, 0, stream>>>(agg, norm_in, W1, b1, xA, N, 1);

    // layer 2: xA -> xB (no relu)
    hipMemsetAsync(agg, 0, (size_t)N * FEAT * sizeof(float), stream);
    k_scatter<<<sthr_blocks, 256, 0, stream>>>(xA, norm_out, src, dst, agg, E);
    k_gemm_node<<<gemm_blocks, 256, 0, stream>>>(agg, norm_in, W2, b2, xB, N, 0);

    // sum-pool
    hipMemsetAsync(gb, 0, (size_t)NG * FEAT * sizeof(float), stream);
    k_pool<<<(nthr + 255) / 256, 256, 0, stream>>>(xB, gid, gb, N);

    // MLP head
    k_lin1<<<NG, 128, 0, stream>>>(gb, l1W, l1b, h1);
    k_lin2<<<NG, 256, 0, stream>>>(h1, l2W, l2b, out);
}

// Round 2
// 591.972 us; speedup vs baseline: 8.3978x; 8.3978x over previous
//
#include <hip/hip_runtime.h>
#include <hip/hip_bf16.h>

// SEAL GCN: 3x GraphConv(norm=both) -> SumPool(graph_id sorted) -> MLP(128->128 relu ->200)
// N=50000 nodes, E=800000 edges, feat=128, 512 graphs. All fp32.
// R2: CSR-gather SpMM (no float atomics), LDS-tiled W GEMM, segmented pool.

#define FEAT 128
#define NG 512

// ---------------- int degree histograms ----------------
__global__ void k_degree_i(const int* __restrict__ src, const int* __restrict__ dst,
                           int* __restrict__ cnt_out, int* __restrict__ cnt_in, int E) {
    int e = blockIdx.x * blockDim.x + threadIdx.x;
    if (e < E) {
        atomicAdd(&cnt_out[src[e]], 1);
        atomicAdd(&cnt_in[dst[e]], 1);
    }
}

__global__ void k_norm(const int* __restrict__ cnt_out, const int* __restrict__ cnt_in,
                       float* __restrict__ norm_out, float* __restrict__ norm_in, int N) {
    int i = blockIdx.x * blockDim.x + threadIdx.x;
    if (i < N) {
        norm_out[i] = rsqrtf(fmaxf((float)cnt_out[i], 1.0f));
        norm_in[i]  = rsqrtf(fmaxf((float)cnt_in[i], 1.0f));
    }
}

// ---------------- 2-level exclusive scan of cnt_in -> row_start ----------------
__global__ void k_scan_local(const int* __restrict__ cnt, int* __restrict__ excl,
                             int* __restrict__ bsum, int N) {
    __shared__ int s[256];
    int x = threadIdx.x;
    int i = blockIdx.x * 256 + x;
    int v = (i < N) ? cnt[i] : 0;
    s[x] = v;
    __syncthreads();
    for (int off = 1; off < 256; off <<= 1) {
        int t = (x >= off) ? s[x - off] : 0;
        __syncthreads();
        s[x] += t;
        __syncthreads();
    }
    if (i < N) excl[i] = s[x] - v;            // exclusive within block
    if (x == 255) bsum[blockIdx.x] = s[255];  // block total
}

__global__ void k_scan_bsum(int* __restrict__ bsum, int* __restrict__ boff, int nb) {
    __shared__ int s[256];
    int x = threadIdx.x;
    int v = (x < nb) ? bsum[x] : 0;
    s[x] = v;
    __syncthreads();
    for (int off = 1; off < 256; off <<= 1) {
        int t = (x >= off) ? s[x - off] : 0;
        __syncthreads();
        s[x] += t;
        __syncthreads();
    }
    if (x < nb) boff[x] = s[x] - v;  // exclusive
}

__global__ void k_add_off(int* __restrict__ row_start, int* __restrict__ cursor,
                          const int* __restrict__ boff, int N) {
    int i = blockIdx.x * blockDim.x + threadIdx.x;
    if (i < N) {
        int v = row_start[i] + boff[i >> 8];
        row_start[i] = v;
        cursor[i] = v;
    }
}

__global__ void k_fill(const int* __restrict__ src, const int* __restrict__ dst,
                       int* __restrict__ cursor, int* __restrict__ csr, int E) {
    int e = blockIdx.x * blockDim.x + threadIdx.x;
    if (e < E) {
        int pos = atomicAdd(&cursor[dst[e]], 1);
        csr[pos] = src[e];
    }
}

// ---------------- build x = concat(init_embed[nid], z_table[z]) ----------------
__global__ void k_build_x(const int* __restrict__ nid, const int* __restrict__ z,
                          const float* __restrict__ emb, const float* __restrict__ zt,
                          float* __restrict__ x, int N) {
    int tid = blockIdx.x * blockDim.x + threadIdx.x;
    int i = tid >> 5, q = tid & 31;
    if (i < N) {
        float4 v;
        if (q < 16) v = ((const float4*)emb)[(size_t)nid[i] * 16 + q];
        else        v = ((const float4*)zt)[(size_t)z[i] * 16 + (q - 16)];
        ((float4*)x)[(size_t)i * 32 + q] = v;
    }
}

// ---------------- gather SpMM: agg[i,:] = nin[i] * sum_{s in N(i)} x[s,:]*nout[s] ----------------
// 32 lanes per node (one float4 column each), 8 nodes per 256-thread block.
__global__ __launch_bounds__(256) void k_gather(
        const float* __restrict__ x, const float* __restrict__ nout,
        const float* __restrict__ nin, const int* __restrict__ csr,
        const int* __restrict__ row_start, const int* __restrict__ cnt_in,
        float* __restrict__ agg, int N) {
    int tid = threadIdx.x;
    int node = blockIdx.x * 8 + (tid >> 5);
    int q = tid & 31;
    if (node >= N) return;
    int base = row_start[node];
    int n = cnt_in[node];
    float4 acc = make_float4(0.f, 0.f, 0.f, 0.f);
    #pragma unroll 2
    for (int j = 0; j < n; j++) {
        int s = csr[base + j];
        float w = nout[s];
        float4 v = ((const float4*)x)[(size_t)s * 32 + q];
        acc.x += v.x * w; acc.y += v.y * w; acc.z += v.z * w; acc.w += v.w * w;
    }
    float ni = nin[node];
    acc.x *= ni; acc.y *= ni; acc.z *= ni; acc.w *= ni;
    ((float4*)agg)[(size_t)node * 32 + q] = acc;
}

// ---------------- per-node GEMM: y[i,:] = relu?(a[i,:] @ W + b) ----------------
// 32 nodes/block, 256 threads: r = tid&31 (node), g = tid>>5 (16-col group).
// W staged in LDS in 32-row tiles. as stride 129 -> conflict-free column reads.
__global__ __launch_bounds__(256) void k_gemm_node(
        const float* __restrict__ a, const float* __restrict__ W,
        const float* __restrict__ bias, float* __restrict__ y, int N, int relu) {
    __shared__ float as[32][129];
    __shared__ float Ws[32][128];
    int nb = blockIdx.x * 32;
    int tid = threadIdx.x;

    // stage 32 a-rows
    for (int t = tid; t < 32 * 32; t += 256) {
        int r = t >> 5, q = t & 31;
        int node = nb + r;
        float4 v = make_float4(0.f, 0.f, 0.f, 0.f);
        if (node < N) v = ((const float4*)a)[(size_t)node * 32 + q];
        as[r][q * 4 + 0] = v.x;
        as[r][q * 4 + 1] = v.y;
        as[r][q * 4 + 2] = v.z;
        as[r][q * 4 + 3] = v.w;
    }

    int r = tid & 31;
    int g = tid >> 5;
    int node = nb + r;

    float4 acc[4];
    #pragma unroll
    for (int c = 0; c < 4; c++) acc[c] = ((const float4*)bias)[g * 4 + c];

    for (int t0 = 0; t0 < FEAT; t0 += 32) {
        __syncthreads();  // first pass also covers as-staging
        {   // stage Ws rows t0..t0+32: thread -> (row kk = tid>>3, col group gg = tid&7)
            int kk = tid >> 3, gg = tid & 7;
            const float4* wr = (const float4*)(W + (size_t)(t0 + kk) * FEAT) + gg * 4;
            float4* wd = (float4*)(&Ws[kk][gg * 16]);
            #pragma unroll
            for (int c = 0; c < 4; c++) wd[c] = wr[c];
        }
        __syncthreads();
        #pragma unroll
        for (int kk = 0; kk < 32; kk++) {
            float av = as[r][t0 + kk];
            const float4* wr4 = (const float4*)(&Ws[kk][g * 16]);
            #pragma unroll
            for (int c = 0; c < 4; c++) {
                float4 wv = wr4[c];
                acc[c].x += av * wv.x;
                acc[c].y += av * wv.y;
                acc[c].z += av * wv.z;
                acc[c].w += av * wv.w;
            }
        }
    }

    if (node < N) {
        float4* yp = (float4*)(y + (size_t)node * FEAT) + g * 4;
        #pragma unroll
        for (int c = 0; c < 4; c++) {
            float4 v = acc[c];
            if (relu) {
                v.x = fmaxf(v.x, 0.f); v.y = fmaxf(v.y, 0.f);
                v.z = fmaxf(v.z, 0.f); v.w = fmaxf(v.w, 0.f);
            }
            yp[c] = v;
        }
    }
}

// ---------------- segmented sum-pool (graph_id sorted): one block per graph ----------------
__global__ void k_pool_seg(const float* __restrict__ x, const int* __restrict__ gid,
                           float* __restrict__ g, int N) {
    int gi = blockIdx.x;
    int j = threadIdx.x;  // 128 threads, one column each
    // lower_bound(gid, gi) and lower_bound(gid, gi+1)
    int lo = 0, hi = N;
    while (lo < hi) { int mid = (lo + hi) >> 1; if (gid[mid] < gi) lo = mid + 1; else hi = mid; }
    int s0 = lo;
    lo = 0; hi = N;
    while (lo < hi) { int mid = (lo + hi) >> 1; if (gid[mid] < gi + 1) lo = mid + 1; else hi = mid; }
    int e0 = lo;
    float acc = 0.f;
    for (int i = s0; i < e0; i++) acc += x[(size_t)i * FEAT + j];
    g[(size_t)gi * FEAT + j] = acc;
}

// ---------------- MLP head ----------------
__global__ void k_lin1(const float* __restrict__ g, const float* __restrict__ W,
                       const float* __restrict__ b, float* __restrict__ h) {
    __shared__ float gs[128];
    int gi = blockIdx.x, j = threadIdx.x;
    gs[j] = g[(size_t)gi * 128 + j];
    __syncthreads();
    float acc = b[j];
    for (int k = 0; k < 128; k++) acc += gs[k] * W[(size_t)k * 128 + j];
    h[(size_t)gi * 128 + j] = fmaxf(acc, 0.f);
}

__global__ void k_lin2(const float* __restrict__ h, const float* __restrict__ W,
                       const float* __restrict__ b, float* __restrict__ out) {
    __shared__ float hs[128];
    int gi = blockIdx.x, j = threadIdx.x;
    if (j < 128) hs[j] = h[(size_t)gi * 128 + j];
    __syncthreads();
    if (j < 200) {
        float acc = b[j];
        for (int k = 0; k < 128; k++) acc += hs[k] * W[(size_t)k * 200 + j];
        out[(size_t)gi * 200 + j] = acc;
    }
}

extern "C" void kernel_launch(void* const* d_in, const int* in_sizes, int n_in,
                              void* d_out, int out_size, void* d_ws, size_t ws_size,
                              hipStream_t stream) {
    const int*   nid = (const int*)d_in[0];
    const int*   z   = (const int*)d_in[1];
    const int*   src = (const int*)d_in[2];
    const int*   dst = (const int*)d_in[3];
    const int*   gid = (const int*)d_in[4];
    const float* emb = (const float*)d_in[5];
    const float* zt  = (const float*)d_in[6];
    const float* W0  = (const float*)d_in[7];
    const float* b0  = (const float*)d_in[8];
    const float* W1  = (const float*)d_in[9];
    const float* b1  = (const float*)d_in[10];
    const float* W2  = (const float*)d_in[11];
    const float* b2  = (const float*)d_in[12];
    const float* l1W = (const float*)d_in[13];
    const float* l1b = (const float*)d_in[14];
    const float* l2W = (const float*)d_in[15];
    const float* l2b = (const float*)d_in[16];
    float* out = (float*)d_out;

    const int N = in_sizes[0];
    const int E = in_sizes[2];
    const int NB = (N + 255) / 256;  // scan blocks (196 for N=50000, must be <=256)

    // ---- workspace layout ----
    size_t NA = (size_t)((N + 63) & ~63);
    float* norm_out = (float*)d_ws;                 // NA
    float* norm_in  = norm_out + NA;                // NA
    float* xA  = norm_in + NA;                      // N*128
    float* agg = xA + (size_t)N * FEAT;             // N*128
    float* gb  = agg + (size_t)N * FEAT;            // 512*128
    float* h1  = gb + (size_t)NG * FEAT;            // 512*128
    int* cnt_out   = (int*)(h1 + (size_t)NG * FEAT);// NA
    int* cnt_in    = cnt_out + NA;                  // NA
    int* row_start = cnt_in + NA;                   // NA
    int* cursor    = row_start + NA;                // NA
    int* bsum      = cursor + NA;                   // 256
    int* boff      = bsum + 256;                    // 256
    int* csr       = boff + 256;                    // E

    // ---- CSR build + norms (graph identical across layers) ----
    hipMemsetAsync(cnt_out, 0, 2 * NA * sizeof(int), stream);
    k_degree_i<<<(E + 255) / 256, 256, 0, stream>>>(src, dst, cnt_out, cnt_in, E);
    k_norm<<<NB, 256, 0, stream>>>(cnt_out, cnt_in, norm_out, norm_in, N);
    k_scan_local<<<NB, 256, 0, stream>>>(cnt_in, row_start, bsum, N);
    k_scan_bsum<<<1, 256, 0, stream>>>(bsum, boff, NB);
    k_add_off<<<NB, 256, 0, stream>>>(row_start, cursor, boff, N);
    k_fill<<<(E + 255) / 256, 256, 0, stream>>>(src, dst, cursor, csr, E);

    // ---- x0 ----
    int nthr = N * 32;
    k_build_x<<<(nthr + 255) / 256, 256, 0, stream>>>(nid, z, emb, zt, xA, N);

    int gat_blocks  = (N + 7) / 8;
    int gemm_blocks = (N + 31) / 32;

    // layer 0
    k_gather<<<gat_blocks, 256, 0, stream>>>(xA, norm_out, norm_in, csr, row_start, cnt_in, agg, N);
    k_gemm_node<<<gemm_blocks, 256, 0, stream>>>(agg, W0, b0, xA, N, 1);
    // layer 1
    k_gather<<<gat_blocks, 256, 0, stream>>>(xA, norm_out, norm_in, csr, row_start, cnt_in, agg, N);
    k_gemm_node<<<gemm_blocks, 256, 0, stream>>>(agg, W1, b1, xA, N, 1);
    // layer 2 (no relu)
    k_gather<<<gat_blocks, 256, 0, stream>>>(xA, norm_out, norm_in, csr, row_start, cnt_in, agg, N);
    k_gemm_node<<<gemm_blocks, 256, 0, stream>>>(agg, W2, b2, xA, N, 0);

    // ---- segmented pool + MLP head ----
    k_pool_seg<<<NG, 128, 0, stream>>>(xA, gid, gb, N);
    k_lin1<<<NG, 128, 0, stream>>>(gb, l1W, l1b, h1);
    k_lin2<<<NG, 256, 0, stream>>>(h1, l2W, l2b, out);
}

// Round 3
// 507.117 us; speedup vs baseline: 9.8030x; 1.1673x over previous
//
#include <hip/hip_runtime.h>
#include <hip/hip_bf16.h>

// SEAL GCN: 3x GraphConv(norm=both) -> SumPool(graph_id sorted) -> MLP(128->128 relu ->200)
// N=50000, E=800000, feat=128, 512 graphs, fp32.
// R3: padded counters (1 per 32B line), degree+build_x fused, gather+GEMM fused,
//     layer-2 GEMM commuted past pool (linearity), fused pool+MLP head.

#define FEAT 128
#define NG 512
#define PAD 8  // counter stride: one counter per 32B line to kill same-line atomic serialization

// ---------------- degree histograms (padded) + build_x, block-partitioned ----------------
__global__ __launch_bounds__(256) void k_deg_bx(
        const int* __restrict__ src, const int* __restrict__ dst,
        int* __restrict__ cnt_out, int* __restrict__ cnt_in,
        const int* __restrict__ nid, const int* __restrict__ z,
        const float* __restrict__ emb, const float* __restrict__ zt,
        float* __restrict__ x, int N, int E, int DB) {
    if ((int)blockIdx.x < DB) {
        int e = blockIdx.x * 256 + threadIdx.x;
        if (e < E) {
            atomicAdd(&cnt_out[src[e] * PAD], 1);
            atomicAdd(&cnt_in[dst[e] * PAD], 1);
        }
    } else {
        int tid = ((int)blockIdx.x - DB) * 256 + threadIdx.x;
        int i = tid >> 5, q = tid & 31;
        if (i < N) {
            float4 v;
            if (q < 16) v = ((const float4*)emb)[(size_t)nid[i] * 16 + q];
            else        v = ((const float4*)zt)[(size_t)z[i] * 16 + (q - 16)];
            ((float4*)x)[(size_t)i * 32 + q] = v;
        }
    }
}

// ---------------- 2-level exclusive scan of cnt_in (padded) -> row_start ----------------
__global__ void k_scan_local(const int* __restrict__ cnt, int* __restrict__ excl,
                             int* __restrict__ bsum, int N) {
    __shared__ int s[256];
    int x = threadIdx.x;
    int i = blockIdx.x * 256 + x;
    int v = (i < N) ? cnt[i * PAD] : 0;
    s[x] = v;
    __syncthreads();
    for (int off = 1; off < 256; off <<= 1) {
        int t = (x >= off) ? s[x - off] : 0;
        __syncthreads();
        s[x] += t;
        __syncthreads();
    }
    if (i < N) excl[i] = s[x] - v;
    if (x == 255) bsum[blockIdx.x] = s[255];
}

__global__ void k_scan_bsum(int* __restrict__ bsum, int* __restrict__ boff, int nb) {
    __shared__ int s[256];
    int x = threadIdx.x;
    int v = (x < nb) ? bsum[x] : 0;
    s[x] = v;
    __syncthreads();
    for (int off = 1; off < 256; off <<= 1) {
        int t = (x >= off) ? s[x - off] : 0;
        __syncthreads();
        s[x] += t;
        __syncthreads();
    }
    if (x < nb) boff[x] = s[x] - v;
}

// add block offsets; init cursor; compute norms (fused)
__global__ void k_add_off_norm(int* __restrict__ row_start, int* __restrict__ cursor,
                               const int* __restrict__ boff,
                               const int* __restrict__ cnt_out, const int* __restrict__ cnt_in,
                               float* __restrict__ norm_out, float* __restrict__ norm_in, int N) {
    int i = blockIdx.x * blockDim.x + threadIdx.x;
    if (i < N) {
        int v = row_start[i] + boff[i >> 8];
        row_start[i] = v;
        cursor[i * PAD] = v;
        norm_out[i] = rsqrtf(fmaxf((float)cnt_out[i * PAD], 1.0f));
        norm_in[i]  = rsqrtf(fmaxf((float)cnt_in[i * PAD], 1.0f));
    }
}

__global__ void k_fill(const int* __restrict__ src, const int* __restrict__ dst,
                       int* __restrict__ cursor, int* __restrict__ csr, int E) {
    int e = blockIdx.x * blockDim.x + threadIdx.x;
    if (e < E) {
        int pos = atomicAdd(&cursor[dst[e] * PAD], 1);
        csr[pos] = src[e];
    }
}

// ---------------- fused layer: gather-SpMM into LDS, then GEMM ----------------
// 32 nodes/block. Gather: 8 lanes/node, each owns 16 cols (4 float4 accs).
// GEMM: r=tid&31 (node), g=tid>>5 (16-col group); as stride 129 -> conflict-free.
__global__ __launch_bounds__(256) void k_layer(
        const float* __restrict__ x, const float* __restrict__ nout,
        const float* __restrict__ nin, const int* __restrict__ csr,
        const int* __restrict__ row_start, const int* __restrict__ cnt_in,
        const float* __restrict__ W, const float* __restrict__ bias,
        float* __restrict__ y, int N, int relu) {
    __shared__ float as[32][129];
    __shared__ float Ws[32][128];
    int tid = threadIdx.x;
    int nb = blockIdx.x * 32;

    // ---- gather phase ----
    {
        int r = tid >> 3;        // node within tile
        int ln = tid & 7;        // col group [ln*16, ln*16+16)
        int node = nb + r;
        float4 a0 = make_float4(0, 0, 0, 0), a1 = a0, a2 = a0, a3 = a0;
        if (node < N) {
            int base = row_start[node];
            int n = cnt_in[node * PAD];
            const float4* xp = (const float4*)x;
            for (int j = 0; j < n; j++) {
                int s = csr[base + j];
                float w = nout[s];
                size_t o = (size_t)s * 32 + ln * 4;
                float4 v0 = xp[o + 0], v1 = xp[o + 1], v2 = xp[o + 2], v3 = xp[o + 3];
                a0.x += v0.x * w; a0.y += v0.y * w; a0.z += v0.z * w; a0.w += v0.w * w;
                a1.x += v1.x * w; a1.y += v1.y * w; a1.z += v1.z * w; a1.w += v1.w * w;
                a2.x += v2.x * w; a2.y += v2.y * w; a2.z += v2.z * w; a2.w += v2.w * w;
                a3.x += v3.x * w; a3.y += v3.y * w; a3.z += v3.z * w; a3.w += v3.w * w;
            }
            float ni = nin[node];
            a0.x *= ni; a0.y *= ni; a0.z *= ni; a0.w *= ni;
            a1.x *= ni; a1.y *= ni; a1.z *= ni; a1.w *= ni;
            a2.x *= ni; a2.y *= ni; a2.z *= ni; a2.w *= ni;
            a3.x *= ni; a3.y *= ni; a3.z *= ni; a3.w *= ni;
        }
        float* ap = &as[r][ln * 16];
        ap[0]  = a0.x; ap[1]  = a0.y; ap[2]  = a0.z; ap[3]  = a0.w;
        ap[4]  = a1.x; ap[5]  = a1.y; ap[6]  = a1.z; ap[7]  = a1.w;
        ap[8]  = a2.x; ap[9]  = a2.y; ap[10] = a2.z; ap[11] = a2.w;
        ap[12] = a3.x; ap[13] = a3.y; ap[14] = a3.z; ap[15] = a3.w;
    }

    // ---- GEMM phase ----
    int r = tid & 31;
    int g = tid >> 5;
    int node = nb + r;

    float4 acc[4];
    #pragma unroll
    for (int c = 0; c < 4; c++) acc[c] = ((const float4*)bias)[g * 4 + c];

    for (int t0 = 0; t0 < FEAT; t0 += 32) {
        __syncthreads();  // first pass also covers as-staging
        {
            int kk = tid >> 3, gg = tid & 7;
            const float4* wr = (const float4*)(W + (size_t)(t0 + kk) * FEAT) + gg * 4;
            float4* wd = (float4*)(&Ws[kk][gg * 16]);
            #pragma unroll
            for (int c = 0; c < 4; c++) wd[c] = wr[c];
        }
        __syncthreads();
        #pragma unroll
        for (int kk = 0; kk < 32; kk++) {
            float av = as[r][t0 + kk];
            const float4* wr4 = (const float4*)(&Ws[kk][g * 16]);
            #pragma unroll
            for (int c = 0; c < 4; c++) {
                float4 wv = wr4[c];
                acc[c].x += av * wv.x;
                acc[c].y += av * wv.y;
                acc[c].z += av * wv.z;
                acc[c].w += av * wv.w;
            }
        }
    }

    if (node < N) {
        float4* yp = (float4*)(y + (size_t)node * FEAT) + g * 4;
        #pragma unroll
        for (int c = 0; c < 4; c++) {
            float4 v = acc[c];
            if (relu) {
                v.x = fmaxf(v.x, 0.f); v.y = fmaxf(v.y, 0.f);
                v.z = fmaxf(v.z, 0.f); v.w = fmaxf(v.w, 0.f);
            }
            yp[c] = v;
        }
    }
}

// ---------------- layer-2 gather only (GEMM commuted past pool) ----------------
__global__ __launch_bounds__(256) void k_gather(
        const float* __restrict__ x, const float* __restrict__ nout,
        const float* __restrict__ nin, const int* __restrict__ csr,
        const int* __restrict__ row_start, const int* __restrict__ cnt_in,
        float* __restrict__ agg, int N) {
    int tid = threadIdx.x;
    int node = blockIdx.x * 8 + (tid >> 5);
    int q = tid & 31;
    if (node >= N) return;
    int base = row_start[node];
    int n = cnt_in[node * PAD];
    float4 acc = make_float4(0.f, 0.f, 0.f, 0.f);
    #pragma unroll 2
    for (int j = 0; j < n; j++) {
        int s = csr[base + j];
        float w = nout[s];
        float4 v = ((const float4*)x)[(size_t)s * 32 + q];
        acc.x += v.x * w; acc.y += v.y * w; acc.z += v.z * w; acc.w += v.w * w;
    }
    float ni = nin[node];
    acc.x *= ni; acc.y *= ni; acc.z *= ni; acc.w *= ni;
    ((float4*)agg)[(size_t)node * 32 + q] = acc;
}

// ---------------- fused pool + (W2,b2) + lin1 + lin2 head ----------------
// One block (256 thr) per graph. out[g] = relu((pool(agg)@W2 + cnt*b2)@l1W + l1b)@l2W + l2b
__global__ __launch_bounds__(256) void k_head(
        const float* __restrict__ agg, const int* __restrict__ gid,
        const float* __restrict__ W2, const float* __restrict__ b2,
        const float* __restrict__ l1W, const float* __restrict__ l1b,
        const float* __restrict__ l2W, const float* __restrict__ l2b,
        float* __restrict__ out, int N) {
    __shared__ float g2[2][128];
    __shared__ float gs[128];
    __shared__ float ys[128];
    __shared__ float hs[128];
    int gi = blockIdx.x, tid = threadIdx.x;

    int lo = 0, hi = N;
    while (lo < hi) { int m = (lo + hi) >> 1; if (gid[m] < gi) lo = m + 1; else hi = m; }
    int s0 = lo;
    lo = 0; hi = N;
    while (lo < hi) { int m = (lo + hi) >> 1; if (gid[m] < gi + 1) lo = m + 1; else hi = m; }
    int e0 = lo;
    float cnt = (float)(e0 - s0);

    int t = tid >> 7, j = tid & 127;
    float p = 0.f;
    for (int i = s0 + t; i < e0; i += 2) p += agg[(size_t)i * FEAT + j];
    g2[t][j] = p;
    __syncthreads();
    if (tid < 128) gs[tid] = g2[0][tid] + g2[1][tid];
    __syncthreads();
    if (tid < 128) {
        float a = cnt * b2[tid];
        for (int k = 0; k < 128; k++) a += gs[k] * W2[(size_t)k * 128 + tid];
        ys[tid] = a;
    }
    __syncthreads();
    if (tid < 128) {
        float a = l1b[tid];
        for (int k = 0; k < 128; k++) a += ys[k] * l1W[(size_t)k * 128 + tid];
        hs[tid] = fmaxf(a, 0.f);
    }
    __syncthreads();
    if (tid < 200) {
        float a = l2b[tid];
        for (int k = 0; k < 128; k++) a += hs[k] * l2W[(size_t)k * 200 + tid];
        out[(size_t)gi * 200 + tid] = a;
    }
}

extern "C" void kernel_launch(void* const* d_in, const int* in_sizes, int n_in,
                              void* d_out, int out_size, void* d_ws, size_t ws_size,
                              hipStream_t stream) {
    const int*   nid = (const int*)d_in[0];
    const int*   z   = (const int*)d_in[1];
    const int*   src = (const int*)d_in[2];
    const int*   dst = (const int*)d_in[3];
    const int*   gid = (const int*)d_in[4];
    const float* emb = (const float*)d_in[5];
    const float* zt  = (const float*)d_in[6];
    const float* W0  = (const float*)d_in[7];
    const float* b0  = (const float*)d_in[8];
    const float* W1  = (const float*)d_in[9];
    const float* b1  = (const float*)d_in[10];
    const float* W2  = (const float*)d_in[11];
    const float* b2  = (const float*)d_in[12];
    const float* l1W = (const float*)d_in[13];
    const float* l1b = (const float*)d_in[14];
    const float* l2W = (const float*)d_in[15];
    const float* l2b = (const float*)d_in[16];
    float* out = (float*)d_out;

    const int N = in_sizes[0];
    const int E = in_sizes[2];
    const int NB = (N + 255) / 256;

    // ---- workspace ----
    size_t NA = (size_t)((N + 63) & ~63);
    float* norm_out = (float*)d_ws;                   // NA
    float* norm_in  = norm_out + NA;                  // NA
    float* xA  = norm_in + NA;                        // N*128
    float* xB  = xA + (size_t)N * FEAT;               // N*128
    float* agg = xB + (size_t)N * FEAT;               // N*128
    int* cnt_out   = (int*)(agg + (size_t)N * FEAT);  // NA*PAD
    int* cnt_in    = cnt_out + NA * PAD;              // NA*PAD
    int* row_start = cnt_in + NA * PAD;               // NA
    int* cursor    = row_start + NA;                  // NA*PAD
    int* bsum      = cursor + NA * PAD;               // 256
    int* boff      = bsum + 256;                      // 256
    int* csr       = boff + 256;                      // E

    // ---- CSR build + norms + x0 (fused/overlapped) ----
    hipMemsetAsync(cnt_out, 0, 2 * NA * PAD * sizeof(int), stream);
    int DB = (E + 255) / 256;
    int XB = (N * 32 + 255) / 256;
    k_deg_bx<<<DB + XB, 256, 0, stream>>>(src, dst, cnt_out, cnt_in, nid, z, emb, zt, xA, N, E, DB);
    k_scan_local<<<NB, 256, 0, stream>>>(cnt_in, row_start, bsum, N);
    k_scan_bsum<<<1, 256, 0, stream>>>(bsum, boff, NB);
    k_add_off_norm<<<NB, 256, 0, stream>>>(row_start, cursor, boff, cnt_out, cnt_in,
                                           norm_out, norm_in, N);
    k_fill<<<(E + 255) / 256, 256, 0, stream>>>(src, dst, cursor, csr, E);

    int lay_blocks = (N + 31) / 32;
    int gat_blocks = (N + 7) / 8;

    // layer 0: xA -> xB (relu), layer 1: xB -> xA (relu)
    k_layer<<<lay_blocks, 256, 0, stream>>>(xA, norm_out, norm_in, csr, row_start, cnt_in, W0, b0, xB, N, 1);
    k_layer<<<lay_blocks, 256, 0, stream>>>(xB, norm_out, norm_in, csr, row_start, cnt_in, W1, b1, xA, N, 1);
    // layer 2: gather only (GEMM folded into head via linearity)
    k_gather<<<gat_blocks, 256, 0, stream>>>(xA, norm_out, norm_in, csr, row_start, cnt_in, agg, N);

    // fused pool + MLP head
    k_head<<<NG, 256, 0, stream>>>(agg, gid, W2, b2, l1W, l1b, l2W, l2b, out, N);
}

// Round 4
// 428.060 us; speedup vs baseline: 11.6135x; 1.1847x over previous
//
#include <hip/hip_runtime.h>
#include <hip/hip_bf16.h>

// SEAL GCN: 3x GraphConv(norm=both) -> SumPool(graph_id sorted) -> MLP(128->128 relu ->200)
// N=50000, E=800000, feat=128, 512 graphs.
// R4: bf16 activations (fp32 accumulate), norm_out folded into producers,
//     de-fused 32-lane gather (no LDS, max occupancy), 64-row GEMM with
//     transposed-A LDS + 4x8 register blocking, PAD=16 counters.

#define FEAT 128
#define NG 512
#define PAD 16  // counter stride: 64B spacing to kill same-line atomic serialization

__device__ __forceinline__ float bf2f(unsigned short u) {
    union { unsigned int i; float f; } v; v.i = ((unsigned int)u) << 16; return v.f;
}
__device__ __forceinline__ unsigned short f2bf(float f) {
    unsigned int u = __float_as_uint(f);
    return (unsigned short)((u + 0x7FFFu + ((u >> 16) & 1u)) >> 16);  // RNE
}

// ---------------- degree histograms (padded) ----------------
__global__ void k_degree(const int* __restrict__ src, const int* __restrict__ dst,
                         int* __restrict__ cnt_out, int* __restrict__ cnt_in, int E) {
    int e = blockIdx.x * blockDim.x + threadIdx.x;
    if (e < E) {
        atomicAdd(&cnt_out[src[e] * PAD], 1);
        atomicAdd(&cnt_in[dst[e] * PAD], 1);
    }
}

// ---------------- 2-level exclusive scan of cnt_in -> row_start ----------------
__global__ void k_scan_local(const int* __restrict__ cnt, int* __restrict__ excl,
                             int* __restrict__ bsum, int N) {
    __shared__ int s[256];
    int x = threadIdx.x;
    int i = blockIdx.x * 256 + x;
    int v = (i < N) ? cnt[i * PAD] : 0;
    s[x] = v;
    __syncthreads();
    for (int off = 1; off < 256; off <<= 1) {
        int t = (x >= off) ? s[x - off] : 0;
        __syncthreads();
        s[x] += t;
        __syncthreads();
    }
    if (i < N) excl[i] = s[x] - v;
    if (x == 255) bsum[blockIdx.x] = s[255];
}

__global__ void k_scan_bsum(int* __restrict__ bsum, int* __restrict__ boff, int nb) {
    __shared__ int s[256];
    int x = threadIdx.x;
    int v = (x < nb) ? bsum[x] : 0;
    s[x] = v;
    __syncthreads();
    for (int off = 1; off < 256; off <<= 1) {
        int t = (x >= off) ? s[x - off] : 0;
        __syncthreads();
        s[x] += t;
        __syncthreads();
    }
    if (x < nb) boff[x] = s[x] - v;
}

// add block offsets; init cursor; compute norms
__global__ void k_add_off_norm(int* __restrict__ row_start, int* __restrict__ cursor,
                               const int* __restrict__ boff,
                               const int* __restrict__ cnt_out, const int* __restrict__ cnt_in,
                               float* __restrict__ norm_out, float* __restrict__ norm_in, int N) {
    int i = blockIdx.x * blockDim.x + threadIdx.x;
    if (i < N) {
        int v = row_start[i] + boff[i >> 8];
        row_start[i] = v;
        cursor[i * PAD] = v;
        norm_out[i] = rsqrtf(fmaxf((float)cnt_out[i * PAD], 1.0f));
        norm_in[i]  = rsqrtf(fmaxf((float)cnt_in[i * PAD], 1.0f));
    }
}

// ---------------- CSR fill + build x0 (bf16, pre-scaled by norm_out), partitioned ----------------
__global__ __launch_bounds__(256) void k_fill_bx(
        const int* __restrict__ src, const int* __restrict__ dst,
        int* __restrict__ cursor, int* __restrict__ csr,
        const int* __restrict__ nid, const int* __restrict__ z,
        const float* __restrict__ emb, const float* __restrict__ zt,
        const float* __restrict__ nout, unsigned short* __restrict__ x,
        int N, int E, int DB) {
    if ((int)blockIdx.x < DB) {
        int e = blockIdx.x * 256 + threadIdx.x;
        if (e < E) {
            int pos = atomicAdd(&cursor[dst[e] * PAD], 1);
            csr[pos] = src[e];
        }
    } else {
        int tid = ((int)blockIdx.x - DB) * 256 + threadIdx.x;
        int i = tid >> 5, q = tid & 31;
        if (i < N) {
            float4 v;
            if (q < 16) v = ((const float4*)emb)[(size_t)nid[i] * 16 + q];
            else        v = ((const float4*)zt)[(size_t)z[i] * 16 + (q - 16)];
            float w = nout[i];
            ushort4 u;
            u.x = f2bf(v.x * w); u.y = f2bf(v.y * w);
            u.z = f2bf(v.z * w); u.w = f2bf(v.w * w);
            ((ushort4*)x)[(size_t)i * 32 + q] = u;
        }
    }
}

// ---------------- gather SpMM: agg[i,:] = nin[i] * sum_{s in N(i)} x[s,:] ----------------
// x is bf16 and pre-scaled by norm_out. 32 lanes/node (ushort4 each), 8 nodes/block, no LDS.
__global__ __launch_bounds__(256) void k_gather(
        const unsigned short* __restrict__ x, const float* __restrict__ nin,
        const int* __restrict__ csr, const int* __restrict__ row_start,
        const int* __restrict__ cnt_in, float* __restrict__ agg, int N) {
    int tid = threadIdx.x;
    int node = blockIdx.x * 8 + (tid >> 5);
    int q = tid & 31;
    if (node >= N) return;
    int base = row_start[node];
    int n = cnt_in[node * PAD];
    float a0 = 0.f, a1 = 0.f, a2 = 0.f, a3 = 0.f;
    const ushort4* xp = (const ushort4*)x;
    #pragma unroll 4
    for (int j = 0; j < n; j++) {
        int s = csr[base + j];
        ushort4 u = xp[(size_t)s * 32 + q];
        a0 += bf2f(u.x); a1 += bf2f(u.y); a2 += bf2f(u.z); a3 += bf2f(u.w);
    }
    float ni = nin[node];
    float4 o = make_float4(a0 * ni, a1 * ni, a2 * ni, a3 * ni);
    ((float4*)agg)[(size_t)node * 32 + q] = o;
}

// ---------------- GEMM: y[i,:] = relu(agg[i,:] @ W + b) * nout[i], bf16 out ----------------
// 64 rows/block, 256 threads: rg=tid&15 (4 rows), cg=tid>>4 (8 cols) -> 4x8 accs.
// asT[128][68]: transposed A, 16B-aligned b128 reads, 2-way (free) bank aliasing.
// Ws b128 reads: 4 distinct addrs/wave, disjoint banks -> conflict-free.
__global__ __launch_bounds__(256) void k_gemm(
        const float* __restrict__ agg, const float* __restrict__ W,
        const float* __restrict__ bias, const float* __restrict__ nout,
        unsigned short* __restrict__ y, int N) {
    __shared__ float asT[128][68];
    __shared__ float Ws[32][128];
    int tid = threadIdx.x;
    int nb = blockIdx.x * 64;

    // stage A transposed: 64 rows x 32 float4
    for (int t = tid; t < 64 * 32; t += 256) {
        int row = t >> 5, q = t & 31;
        int node = nb + row;
        float4 v = make_float4(0.f, 0.f, 0.f, 0.f);
        if (node < N) v = ((const float4*)agg)[(size_t)node * 32 + q];
        asT[q * 4 + 0][row] = v.x;
        asT[q * 4 + 1][row] = v.y;
        asT[q * 4 + 2][row] = v.z;
        asT[q * 4 + 3][row] = v.w;
    }

    int rg = tid & 15, cg = tid >> 4;
    int r0 = rg * 4, c0 = cg * 8;

    float acc[4][8];
    {
        float bb[8];
        #pragma unroll
        for (int c = 0; c < 8; c++) bb[c] = bias[c0 + c];
        #pragma unroll
        for (int i = 0; i < 4; i++)
            #pragma unroll
            for (int c = 0; c < 8; c++) acc[i][c] = bb[c];
    }

    for (int t0 = 0; t0 < FEAT; t0 += 32) {
        __syncthreads();  // first iter: covers asT staging; later: guards Ws overwrite
        for (int t = tid; t < 32 * 32; t += 256) {
            int kk = t >> 5, q = t & 31;
            float4 wv = ((const float4*)(W + (size_t)(t0 + kk) * FEAT))[q];
            *((float4*)&Ws[kk][q * 4]) = wv;
        }
        __syncthreads();
        #pragma unroll
        for (int kk = 0; kk < 32; kk++) {
            float4 av = *((const float4*)&asT[t0 + kk][r0]);
            float4 w0 = *((const float4*)&Ws[kk][c0]);
            float4 w1 = *((const float4*)&Ws[kk][c0 + 4]);
            float a[4] = {av.x, av.y, av.z, av.w};
            float w[8] = {w0.x, w0.y, w0.z, w0.w, w1.x, w1.y, w1.z, w1.w};
            #pragma unroll
            for (int i = 0; i < 4; i++)
                #pragma unroll
                for (int c = 0; c < 8; c++)
                    acc[i][c] += a[i] * w[c];
        }
    }

    #pragma unroll
    for (int i = 0; i < 4; i++) {
        int node = nb + r0 + i;
        if (node < N) {
            float s = nout[node];
            float v[8];
            #pragma unroll
            for (int c = 0; c < 8; c++) v[c] = fmaxf(acc[i][c], 0.f) * s;
            ushort4 u0, u1;
            u0.x = f2bf(v[0]); u0.y = f2bf(v[1]); u0.z = f2bf(v[2]); u0.w = f2bf(v[3]);
            u1.x = f2bf(v[4]); u1.y = f2bf(v[5]); u1.z = f2bf(v[6]); u1.w = f2bf(v[7]);
            ushort4* yp = (ushort4*)(y + (size_t)node * FEAT + c0);
            yp[0] = u0; yp[1] = u1;
        }
    }
}

// ---------------- fused pool + (W2,b2) + lin1 + lin2 head ----------------
__global__ __launch_bounds__(256) void k_head(
        const float* __restrict__ agg, const int* __restrict__ gid,
        const float* __restrict__ W2, const float* __restrict__ b2,
        const float* __restrict__ l1W, const float* __restrict__ l1b,
        const float* __restrict__ l2W, const float* __restrict__ l2b,
        float* __restrict__ out, int N) {
    __shared__ float g2[2][128];
    __shared__ float gs[128];
    __shared__ float ys[128];
    __shared__ float hs[128];
    int gi = blockIdx.x, tid = threadIdx.x;

    int lo = 0, hi = N;
    while (lo < hi) { int m = (lo + hi) >> 1; if (gid[m] < gi) lo = m + 1; else hi = m; }
    int s0 = lo;
    lo = 0; hi = N;
    while (lo < hi) { int m = (lo + hi) >> 1; if (gid[m] < gi + 1) lo = m + 1; else hi = m; }
    int e0 = lo;
    float cnt = (float)(e0 - s0);

    int t = tid >> 7, j = tid & 127;
    float p = 0.f;
    for (int i = s0 + t; i < e0; i += 2) p += agg[(size_t)i * FEAT + j];
    g2[t][j] = p;
    __syncthreads();
    if (tid < 128) gs[tid] = g2[0][tid] + g2[1][tid];
    __syncthreads();
    if (tid < 128) {
        float a = cnt * b2[tid];
        for (int k = 0; k < 128; k++) a += gs[k] * W2[(size_t)k * 128 + tid];
        ys[tid] = a;
    }
    __syncthreads();
    if (tid < 128) {
        float a = l1b[tid];
        for (int k = 0; k < 128; k++) a += ys[k] * l1W[(size_t)k * 128 + tid];
        hs[tid] = fmaxf(a, 0.f);
    }
    __syncthreads();
    if (tid < 200) {
        float a = l2b[tid];
        for (int k = 0; k < 128; k++) a += hs[k] * l2W[(size_t)k * 200 + tid];
        out[(size_t)gi * 200 + tid] = a;
    }
}

extern "C" void kernel_launch(void* const* d_in, const int* in_sizes, int n_in,
                              void* d_out, int out_size, void* d_ws, size_t ws_size,
                              hipStream_t stream) {
    const int*   nid = (const int*)d_in[0];
    const int*   z   = (const int*)d_in[1];
    const int*   src = (const int*)d_in[2];
    const int*   dst = (const int*)d_in[3];
    const int*   gid = (const int*)d_in[4];
    const float* emb = (const float*)d_in[5];
    const float* zt  = (const float*)d_in[6];
    const float* W0  = (const float*)d_in[7];
    const float* b0  = (const float*)d_in[8];
    const float* W1  = (const float*)d_in[9];
    const float* b1  = (const float*)d_in[10];
    const float* W2  = (const float*)d_in[11];
    const float* b2  = (const float*)d_in[12];
    const float* l1W = (const float*)d_in[13];
    const float* l1b = (const float*)d_in[14];
    const float* l2W = (const float*)d_in[15];
    const float* l2b = (const float*)d_in[16];
    float* out = (float*)d_out;

    const int N = in_sizes[0];
    const int E = in_sizes[2];
    const int NB = (N + 255) / 256;

    // ---- workspace ----
    size_t NA = (size_t)((N + 63) & ~63);
    float* norm_out = (float*)d_ws;                      // NA
    float* norm_in  = norm_out + NA;                     // NA
    float* agg = norm_in + NA;                           // N*128 fp32
    unsigned short* xA = (unsigned short*)(agg + (size_t)N * FEAT);  // N*128 bf16
    unsigned short* xB = xA + (size_t)N * FEAT;          // N*128 bf16
    int* cnt_out   = (int*)(xB + (size_t)N * FEAT);      // NA*PAD
    int* cnt_in    = cnt_out + NA * PAD;                 // NA*PAD
    int* row_start = cnt_in + NA * PAD;                  // NA
    int* cursor    = row_start + NA;                     // NA*PAD
    int* bsum      = cursor + NA * PAD;                  // 256
    int* boff      = bsum + 256;                         // 256
    int* csr       = boff + 256;                         // E

    // ---- CSR build + norms ----
    hipMemsetAsync(cnt_out, 0, 2 * NA * PAD * sizeof(int), stream);
    k_degree<<<(E + 255) / 256, 256, 0, stream>>>(src, dst, cnt_out, cnt_in, E);
    k_scan_local<<<NB, 256, 0, stream>>>(cnt_in, row_start, bsum, N);
    k_scan_bsum<<<1, 256, 0, stream>>>(bsum, boff, NB);
    k_add_off_norm<<<NB, 256, 0, stream>>>(row_start, cursor, boff, cnt_out, cnt_in,
                                           norm_out, norm_in, N);
    // fill CSR + build x0 (bf16, pre-scaled by norm_out) in one partitioned launch
    int DB = (E + 255) / 256;
    int XB = (N * 32 + 255) / 256;
    k_fill_bx<<<DB + XB, 256, 0, stream>>>(src, dst, cursor, csr, nid, z, emb, zt,
                                           norm_out, xA, N, E, DB);

    int gat_blocks  = (N + 7) / 8;
    int gemm_blocks = (N + 63) / 64;

    // layer 0: xA -> agg -> xB
    k_gather<<<gat_blocks, 256, 0, stream>>>(xA, norm_in, csr, row_start, cnt_in, agg, N);
    k_gemm<<<gemm_blocks, 256, 0, stream>>>(agg, W0, b0, norm_out, xB, N);
    // layer 1: xB -> agg -> xA
    k_gather<<<gat_blocks, 256, 0, stream>>>(xB, norm_in, csr, row_start, cnt_in, agg, N);
    k_gemm<<<gemm_blocks, 256, 0, stream>>>(agg, W1, b1, norm_out, xA, N);
    // layer 2: gather only (GEMM commuted past pool via linearity)
    k_gather<<<gat_blocks, 256, 0, stream>>>(xA, norm_in, csr, row_start, cnt_in, agg, N);

    // fused pool + MLP head
    k_head<<<NG, 256, 0, stream>>>(agg, gid, W2, b2, l1W, l1b, l2W, l2b, out, N);
}